// Round 1
// baseline (646.631 us; speedup 1.0000x reference)
//
#include <hip/hip_runtime.h>
#include <hip/hip_bf16.h>

// KNN: points (8,4096,3) f32, features (8,4096,64) f32.
// out (8,4096,16,128) f32: [center 64 | knn 64] per (b, i, k).
// Neighbors = 16 nearest excluding self, ascending distance, ties -> lower index
// (matches lax.top_k(-dist, 17)[:,:,1:] since self is always rank 0).

#define BATCH 8
#define NPTS 4096
#define FDIM 64
#define KNN 16
#define QPB 64                 // queries per block
#define NSUB 4                 // sub-threads (candidate partitions) per query
#define CPL (NPTS / NSUB)      // candidates per lane = 1024
#define THREADS 256

__global__ __launch_bounds__(THREADS, 2)
void knn_kernel(const float* __restrict__ points,
                const float* __restrict__ features,
                float* __restrict__ out) {
    __shared__ float2 sxy[NPTS];                       // 32 KB
    __shared__ float  szl[NPTS];                       // 16 KB
    __shared__ float  smd[QPB * NSUB * KNN];           // 16 KB  per-sub sorted dists
    __shared__ unsigned short smi[QPB * NSUB * KNN];   //  8 KB  per-sub sorted idx
    __shared__ unsigned short sidx[QPB * KNN];         //  2 KB  final merged idx

    const int tid = threadIdx.x;
    const int b = blockIdx.x >> 6;                     // / (NPTS/QPB)
    const int qbase = (blockIdx.x & 63) << 6;          // * QPB
    const float* pb = points + (size_t)b * NPTS * 3;

    // ---- stage this batch's points into LDS ----
    for (int p = tid; p < NPTS; p += THREADS) {
        float x = pb[p * 3 + 0];
        float y = pb[p * 3 + 1];
        float z = pb[p * 3 + 2];
        sxy[p] = make_float2(x, y);
        szl[p] = z;
    }
    __syncthreads();

    const int q   = tid & (QPB - 1);   // query within block
    const int sub = tid >> 6;          // candidate partition; uniform per wave
    const int qg0 = qbase + q;         // query index within batch

    const float2 qxy = sxy[qg0];
    const float  qz  = szl[qg0];

    // per-lane sorted top-16 (ascending), static indexing only
    float bd[KNN];
    int   bi[KNN];
#pragma unroll
    for (int s = 0; s < KNN; ++s) { bd[s] = __builtin_inff(); bi[s] = 0; }

    const int j0 = sub * CPL;
    for (int jj = 0; jj < CPL; ++jj) {
        const int j = j0 + jj;
        const float2 pxy = sxy[j];     // broadcast: all lanes in wave read same addr
        const float  pz  = szl[j];
        const float dx = qxy.x - pxy.x;
        const float dy = qxy.y - pxy.y;
        const float dz = qz - pz;
        // match numpy: ((dx*dx + dy*dy) + dz*dz), no FMA contraction
        float d = __fadd_rn(__fadd_rn(__fmul_rn(dx, dx), __fmul_rn(dy, dy)),
                            __fmul_rn(dz, dz));
        if (j == qg0) d = __builtin_inff();   // exclude self
        if (d < bd[KNN - 1]) {
            // unrolled sorted-insert; within-thread ties impossible to misorder
            // (j strictly increasing, strict < keeps earlier index first)
#pragma unroll
            for (int p = KNN - 1; p > 0; --p) {
                const bool down = d < bd[p - 1];
                const bool here = !down && (d < bd[p]);
                bd[p] = down ? bd[p - 1] : (here ? d : bd[p]);
                bi[p] = down ? bi[p - 1] : (here ? j : bi[p]);
            }
            if (d < bd[0]) { bd[0] = d; bi[0] = j; }
        }
    }

    // ---- dump per-sub lists to LDS ----
    const int lbase = (q * NSUB + sub) * KNN;
#pragma unroll
    for (int s = 0; s < KNN; ++s) {
        smd[lbase + s] = bd[s];
        smi[lbase + s] = (unsigned short)bi[s];
    }
    __syncthreads();

    // ---- 4-way merge (one thread per query); ties prefer lower sub = lower idx ----
    if (tid < QPB) {
        int p0 = 0, p1 = 0, p2 = 0, p3 = 0;
        const int base = tid * NSUB * KNN;
        for (int s = 0; s < KNN; ++s) {
            const float d0 = smd[base + 0 * KNN + p0];
            const float d1 = smd[base + 1 * KNN + p1];
            const float d2 = smd[base + 2 * KNN + p2];
            const float d3 = smd[base + 3 * KNN + p3];
            int sel = 0; float dm = d0;
            if (d1 < dm) { sel = 1; dm = d1; }
            if (d2 < dm) { sel = 2; dm = d2; }
            if (d3 < dm) { sel = 3; dm = d3; }
            const int psel = (sel == 0) ? p0 : (sel == 1) ? p1 : (sel == 2) ? p2 : p3;
            sidx[tid * KNN + s] = smi[base + sel * KNN + psel];
            p0 += (sel == 0); p1 += (sel == 1); p2 += (sel == 2); p3 += (sel == 3);
        }
    }
    __syncthreads();

    // ---- gather + write: 64 q x 16 k x 128 c floats = 32768 float4 per block ----
    const float* fb = features + (size_t)b * NPTS * FDIM;
    float* ob = out + (size_t)b * NPTS * (KNN * 2 * FDIM);
#pragma unroll 2
    for (int it = 0; it < 128; ++it) {
        const int flat = it * THREADS + tid;
        const int c4 = flat & 31;           // float4 column 0..31
        const int k  = (flat >> 5) & 15;
        const int qq = flat >> 9;           // 0..63
        const int qg = qbase + qq;
        const int row = (c4 < 16) ? qg : (int)sidx[qq * KNN + k];
        const float4 v = *(const float4*)(fb + (size_t)row * FDIM + ((c4 & 15) << 2));
        *(float4*)(ob + (((size_t)(qg * KNN + k)) << 7) + (c4 << 2)) = v;
    }
}

extern "C" void kernel_launch(void* const* d_in, const int* in_sizes, int n_in,
                              void* d_out, int out_size, void* d_ws, size_t ws_size,
                              hipStream_t stream) {
    const float* points   = (const float*)d_in[0];
    const float* features = (const float*)d_in[1];
    float* out = (float*)d_out;
    const int grid = BATCH * (NPTS / QPB);   // 512 blocks
    knn_kernel<<<dim3(grid), dim3(THREADS), 0, stream>>>(points, features, out);
}